// Round 3
// baseline (225.805 us; speedup 1.0000x reference)
//
#include <hip/hip_runtime.h>
#include <math.h>

#define NB 32
#define CC 512
#define HW 1024
#define NJ 10

// Inter-kernel gap buffer in module device memory (workspace stays unused;
// its poison-fill is unconditional anyway). K1 fully overwrites before K2.
__device__ float g_gap[NB * CC];

__device__ __forceinline__ float wave_reduce(float s) {
#pragma unroll
  for (int off = 32; off; off >>= 1) s += __shfl_down(s, off, 64);
  return s;
}

// K1: gap[n,c] = mean over HW. 1024 blocks x 256 threads. ~11 us, 80% HBM —
// at roofline. Side effect: pulls all of x (67 MB) into the 256 MB L3.
__global__ __launch_bounds__(256) void k_gap(const float* __restrict__ x) {
  int wv = threadIdx.x >> 6, lane = threadIdx.x & 63;
  int r0 = blockIdx.x * 16;
#pragma unroll
  for (int it = 0; it < 4; ++it) {
    int row = r0 + wv * 4 + it;
    const float4* xp = (const float4*)x + (size_t)row * 256;
    float s = 0.f;
#pragma unroll
    for (int k = 0; k < 4; ++k) {
      float4 v = xp[lane + 64 * k];
      s += v.x + v.y + v.z + v.w;
    }
    s = wave_reduce(s);
    if (lane == 0) g_gap[row] = s * (1.0f / 1024.0f);
  }
}

// K2: fused q/softmax-moments/output. Block = (n, pblk): 512 ch x 64 pos.
// v2: x is STREAMED from L3 in phases B and C instead of being cached in a
// 64-VGPR register array. Peak live regs ~75 (acc[10] float4 + 4 in-flight
// loads) -> __launch_bounds__(512,6) caps at 85 VGPR -> 6 waves/SIMD ->
// 3 blocks/CU, so one block's store tail overlaps another's compute.
__global__ __launch_bounds__(512, 6) void k_fused(const float* __restrict__ x,
                                                  const float* __restrict__ wq,
                                                  const float* __restrict__ bq,
                                                  float* __restrict__ out) {
  int n = blockIdx.x >> 4, pblk = blockIdx.x & 15;
  int t = threadIdx.x;
  int cg = t >> 4, pg = t & 15;
  int wv = t >> 6, lane = t & 63;

  __shared__ float qs[CC];
  __shared__ float wred[8][NJ];
  __shared__ float4 sred[8][16][NJ + 1];  // +1 float4 pad: no 4-way conflict
  __shared__ float4 sfin[16][NJ + 1];
  __shared__ float invZ_sh;

  const float cj[NJ] = {1.f, 1.f, 0.5f, 1.f / 6.f, 1.f / 24.f, 1.f / 120.f,
                        1.f / 720.f, 1.f / 5040.f, 1.f / 40320.f, 1.f / 362880.f};

  const float4* x4 = (const float4*)x;
  size_t base = (size_t)(n * CC + cg * 16) * 256 + (size_t)pblk * 16 + pg;

  // ---- phase Q: q = sigmoid(conv5(gap)+b); wave partials of P_j ----
  {
    int c = t;  // 512 threads == 512 channels
    const float* g = g_gap + n * CC;
    float z = bq[0];
#pragma unroll
    for (int k = 0; k < 5; ++k) {
      int idx = c + k - 2;
      float gv = (idx >= 0 && idx < CC) ? g[idx] : 0.f;
      z = fmaf(gv, wq[k], z);
    }
    float qv = 1.f / (1.f + expf(-z));
    qs[c] = qv;
    float pj[NJ];
    float pw = 1.f;
#pragma unroll
    for (int j = 0; j < NJ; ++j) { pj[j] = pw; pw *= qv; }
#pragma unroll
    for (int j = 0; j < NJ; ++j) pj[j] = wave_reduce(pj[j]);
    if (lane == 0) {
#pragma unroll
      for (int j = 0; j < NJ; ++j) wred[wv][j] = pj[j];
    }
  }
  __syncthreads();
  if (t == 0) {
    float Z = 0.f;
#pragma unroll
    for (int j = 0; j < NJ; ++j) {
      float P = 0.f;
#pragma unroll
      for (int w8 = 0; w8 < 8; ++w8) P += wred[w8][j];
      Z = fmaf(cj[j] * P, P, Z);
    }
    invZ_sh = 1.f / Z;  // read after the NEXT __syncthreads
  }

  // ---- phase B: moment accumulation, x streamed from L3 ----
  float4 acc[NJ];
#pragma unroll
  for (int j = 0; j < NJ; ++j) acc[j] = make_float4(0.f, 0.f, 0.f, 0.f);
#pragma unroll 4
  for (int i = 0; i < 16; ++i) {
    float qc = qs[cg * 16 + i];
    float4 v = x4[base + (size_t)i * 256];
    float w = 1.f;
#pragma unroll
    for (int j = 0; j < NJ; ++j) {
      acc[j].x = fmaf(w, v.x, acc[j].x);
      acc[j].y = fmaf(w, v.y, acc[j].y);
      acc[j].z = fmaf(w, v.z, acc[j].z);
      acc[j].w = fmaf(w, v.w, acc[j].w);
      w *= qc;
    }
  }
  // reduce over the 4 cg within this wave (lane bits 4,5)
#pragma unroll
  for (int j = 0; j < NJ; ++j) {
    acc[j].x += __shfl_xor(acc[j].x, 16, 64);
    acc[j].y += __shfl_xor(acc[j].y, 16, 64);
    acc[j].z += __shfl_xor(acc[j].z, 16, 64);
    acc[j].w += __shfl_xor(acc[j].w, 16, 64);
    acc[j].x += __shfl_xor(acc[j].x, 32, 64);
    acc[j].y += __shfl_xor(acc[j].y, 32, 64);
    acc[j].z += __shfl_xor(acc[j].z, 32, 64);
    acc[j].w += __shfl_xor(acc[j].w, 32, 64);
  }
  if (lane < 16) {
#pragma unroll
    for (int j = 0; j < NJ; ++j) sred[wv][lane][j] = acc[j];
  }
  __syncthreads();
  // cross-wave tree: 160 bins (16 pg x 10 j), fold in invZ * 1/j!
  if (t < 160) {
    int pp = t / NJ, j = t - pp * NJ;
    float4 a = make_float4(0.f, 0.f, 0.f, 0.f);
#pragma unroll
    for (int w8 = 0; w8 < 8; ++w8) {
      float4 v = sred[w8][pp][j];
      a.x += v.x; a.y += v.y; a.z += v.z; a.w += v.w;
    }
    float sc = cj[j] * invZ_sh;
    a.x *= sc; a.y *= sc; a.z *= sc; a.w *= sc;
    sfin[pp][j] = a;
  }
  __syncthreads();

  // ---- phase C: out = x * att, x streamed again (L3-resident) ----
  float4 sj[NJ];
#pragma unroll
  for (int j = 0; j < NJ; ++j) sj[j] = sfin[pg][j];
  float4* o4 = (float4*)out;
#pragma unroll 4
  for (int i = 0; i < 16; ++i) {
    float qd = qs[cg * 16 + i];
    float w = 1.f;
    float4 att = make_float4(0.f, 0.f, 0.f, 0.f);
#pragma unroll
    for (int j = 0; j < NJ; ++j) {
      att.x = fmaf(w, sj[j].x, att.x);
      att.y = fmaf(w, sj[j].y, att.y);
      att.z = fmaf(w, sj[j].z, att.z);
      att.w = fmaf(w, sj[j].w, att.w);
      w *= qd;
    }
    float4 v = x4[base + (size_t)i * 256];
    float4 o;
    o.x = v.x * att.x; o.y = v.y * att.y;
    o.z = v.z * att.z; o.w = v.w * att.w;
    o4[base + (size_t)i * 256] = o;
  }
}

extern "C" void kernel_launch(void* const* d_in, const int* in_sizes, int n_in,
                              void* d_out, int out_size, void* d_ws, size_t ws_size,
                              hipStream_t stream) {
  const float* x  = (const float*)d_in[0];
  const float* wq = (const float*)d_in[1];
  const float* bq = (const float*)d_in[2];
  float* out = (float*)d_out;
  (void)d_ws; (void)ws_size;  // workspace intentionally unused

  k_gap<<<NB * CC / 16, 256, 0, stream>>>(x);
  k_fused<<<NB * 16, 512, 0, stream>>>(x, wq, bq, out);
}

// Round 4
// 167.451 us; speedup vs baseline: 1.3485x; 1.3485x over previous
//
#include <hip/hip_runtime.h>
#include <math.h>

#define NB 32
#define CC 512
#define HW 1024
#define NJ 10

// Inter-kernel gap buffer in module device memory. K1 fully overwrites it
// every invocation before K2 reads it — no stale-state dependence.
__device__ float g_gap[NB * CC];

__device__ __forceinline__ float wave_reduce(float s) {
#pragma unroll
  for (int off = 32; off; off >>= 1) s += __shfl_down(s, off, 64);
  return s;
}

// K1: gap[n,c] = mean over HW. ~11 us at 80% HBM — rooflined.
// Side effect: pulls all of x (67 MB) into the 256 MB L3 for K2.
__global__ __launch_bounds__(256) void k_gap(const float* __restrict__ x) {
  int wv = threadIdx.x >> 6, lane = threadIdx.x & 63;
  int r0 = blockIdx.x * 16;
#pragma unroll
  for (int it = 0; it < 4; ++it) {
    int row = r0 + wv * 4 + it;
    const float4* xp = (const float4*)x + (size_t)row * 256;
    float s = 0.f;
#pragma unroll
    for (int k = 0; k < 4; ++k) {
      float4 v = xp[lane + 64 * k];
      s += v.x + v.y + v.z + v.w;
    }
    s = wave_reduce(s);
    if (lane == 0) g_gap[row] = s * (1.0f / 1024.0f);
  }
}

// K2: fused q/softmax-moments/output. Block = (n, pblk): 512 ch x 64 pos.
// Thread (cg,pg) caches x[cg*16..+15][pblk*16+pg] in registers (xv[16], 64 VGPR).
// v3 vs round-2: phase B computes its 10 moments in TWO passes of 5
// (acc[5] = 20 VGPR instead of acc[10] = 40), cutting peak live regs to
// ~115, so __launch_bounds__(512,4) (cap 128 VGPR) fits WITHOUT spilling
// -> 2 blocks/CU -> one block's store tail / serial sections overlap the
// other block's compute. FMA & shuffle counts unchanged.
__global__ __launch_bounds__(512, 4) void k_fused(const float* __restrict__ x,
                                                  const float* __restrict__ wq,
                                                  const float* __restrict__ bq,
                                                  float* __restrict__ out) {
  int n = blockIdx.x >> 4, pblk = blockIdx.x & 15;
  int t = threadIdx.x;
  int cg = t >> 4, pg = t & 15;
  int wv = t >> 6, lane = t & 63;

  __shared__ float qs[CC];
  __shared__ float wred[8][NJ];
  __shared__ float4 sred[8][16][NJ + 1];  // +1 float4 pad: no 4-way conflict
  __shared__ float4 sfin[16][NJ + 1];
  __shared__ float invZ_sh;

  const float cj[NJ] = {1.f, 1.f, 0.5f, 1.f / 6.f, 1.f / 24.f, 1.f / 120.f,
                        1.f / 720.f, 1.f / 5040.f, 1.f / 40320.f, 1.f / 362880.f};

  // ---- load x tile into registers (read x exactly once in this kernel) ----
  float4 xv[16];
  const float4* x4 = (const float4*)x;
  size_t base = (size_t)(n * CC + cg * 16) * 256 + (size_t)pblk * 16 + pg;
#pragma unroll
  for (int i = 0; i < 16; ++i) xv[i] = x4[base + (size_t)i * 256];

  // ---- phase Q: q = sigmoid(conv5(gap)+b); wave partials of P_j ----
  {
    int c = t;  // 512 threads == 512 channels
    const float* g = g_gap + n * CC;
    float z = bq[0];
#pragma unroll
    for (int k = 0; k < 5; ++k) {
      int idx = c + k - 2;
      float gv = (idx >= 0 && idx < CC) ? g[idx] : 0.f;
      z = fmaf(gv, wq[k], z);
    }
    float qv = 1.f / (1.f + expf(-z));
    qs[c] = qv;
    float pj[NJ];
    float pw = 1.f;
#pragma unroll
    for (int j = 0; j < NJ; ++j) { pj[j] = pw; pw *= qv; }
#pragma unroll
    for (int j = 0; j < NJ; ++j) pj[j] = wave_reduce(pj[j]);
    if (lane == 0) {
#pragma unroll
      for (int j = 0; j < NJ; ++j) wred[wv][j] = pj[j];
    }
  }
  __syncthreads();
  if (t == 0) {
    float Z = 0.f;
#pragma unroll
    for (int j = 0; j < NJ; ++j) {
      float P = 0.f;
#pragma unroll
      for (int w8 = 0; w8 < 8; ++w8) P += wred[w8][j];
      Z = fmaf(cj[j] * P, P, Z);
    }
    invZ_sh = 1.f / Z;  // read after the NEXT __syncthreads
  }

  // ---- phase B: moments in two passes of 5 (acc[5] = 20 VGPR live) ----
#pragma unroll
  for (int half = 0; half < 2; ++half) {
    float4 acc[5];
#pragma unroll
    for (int j = 0; j < 5; ++j) acc[j] = make_float4(0.f, 0.f, 0.f, 0.f);
#pragma unroll
    for (int i = 0; i < 16; ++i) {
      float qc = qs[cg * 16 + i];
      float w;
      if (half == 0) {
        w = 1.f;
      } else {
        float q2 = qc * qc;
        float q4 = q2 * q2;
        w = q4 * qc;  // qc^5
      }
      float4 v = xv[i];
#pragma unroll
      for (int j = 0; j < 5; ++j) {
        acc[j].x = fmaf(w, v.x, acc[j].x);
        acc[j].y = fmaf(w, v.y, acc[j].y);
        acc[j].z = fmaf(w, v.z, acc[j].z);
        acc[j].w = fmaf(w, v.w, acc[j].w);
        w *= qc;
      }
    }
    // reduce over the 4 cg within this wave (lane bits 4,5)
#pragma unroll
    for (int j = 0; j < 5; ++j) {
      acc[j].x += __shfl_xor(acc[j].x, 16, 64);
      acc[j].y += __shfl_xor(acc[j].y, 16, 64);
      acc[j].z += __shfl_xor(acc[j].z, 16, 64);
      acc[j].w += __shfl_xor(acc[j].w, 16, 64);
      acc[j].x += __shfl_xor(acc[j].x, 32, 64);
      acc[j].y += __shfl_xor(acc[j].y, 32, 64);
      acc[j].z += __shfl_xor(acc[j].z, 32, 64);
      acc[j].w += __shfl_xor(acc[j].w, 32, 64);
    }
    if (lane < 16) {
#pragma unroll
      for (int j = 0; j < 5; ++j) sred[wv][lane][half * 5 + j] = acc[j];
    }
  }
  __syncthreads();
  // cross-wave tree: 160 bins (16 pg x 10 j), fold in invZ * 1/j!
  if (t < 160) {
    int pp = t / NJ, j = t - pp * NJ;
    float4 a = make_float4(0.f, 0.f, 0.f, 0.f);
#pragma unroll
    for (int w8 = 0; w8 < 8; ++w8) {
      float4 v = sred[w8][pp][j];
      a.x += v.x; a.y += v.y; a.z += v.z; a.w += v.w;
    }
    float sc = cj[j] * invZ_sh;
    a.x *= sc; a.y *= sc; a.z *= sc; a.w *= sc;
    sfin[pp][j] = a;
  }
  __syncthreads();

  // ---- phase C: out = x * att, x still in registers ----
  float4 sj[NJ];
#pragma unroll
  for (int j = 0; j < NJ; ++j) sj[j] = sfin[pg][j];
  float4* o4 = (float4*)out;
#pragma unroll
  for (int i = 0; i < 16; ++i) {
    float qd = qs[cg * 16 + i];
    float w = 1.f;
    float4 att = make_float4(0.f, 0.f, 0.f, 0.f);
#pragma unroll
    for (int j = 0; j < NJ; ++j) {
      att.x = fmaf(w, sj[j].x, att.x);
      att.y = fmaf(w, sj[j].y, att.y);
      att.z = fmaf(w, sj[j].z, att.z);
      att.w = fmaf(w, sj[j].w, att.w);
      w *= qd;
    }
    float4 xvv = xv[i];
    float4 o;
    o.x = xvv.x * att.x; o.y = xvv.y * att.y;
    o.z = xvv.z * att.z; o.w = xvv.w * att.w;
    o4[base + (size_t)i * 256] = o;
  }
}

extern "C" void kernel_launch(void* const* d_in, const int* in_sizes, int n_in,
                              void* d_out, int out_size, void* d_ws, size_t ws_size,
                              hipStream_t stream) {
  const float* x  = (const float*)d_in[0];
  const float* wq = (const float*)d_in[1];
  const float* bq = (const float*)d_in[2];
  float* out = (float*)d_out;
  (void)d_ws; (void)ws_size;  // workspace intentionally unused

  k_gap<<<NB * CC / 16, 256, 0, stream>>>(x);
  k_fused<<<NB * 16, 512, 0, stream>>>(x, wq, bq, out);
}

// Round 5
// 133.023 us; speedup vs baseline: 1.6975x; 1.2588x over previous
//
#include <hip/hip_runtime.h>
#include <math.h>

#define NB 32
#define CC 512
#define HW 1024
#define NJ 10

// Inter-kernel gap buffer in module device memory. K1 fully overwrites it
// every invocation before K2 reads it — no stale-state dependence.
__device__ float g_gap[NB * CC];

__device__ __forceinline__ float wave_reduce(float s) {
#pragma unroll
  for (int off = 32; off; off >>= 1) s += __shfl_down(s, off, 64);
  return s;
}

// K1: gap[n,c] = mean over HW. ~11 us at 80% HBM — rooflined.
// Side effect: pulls all of x (67 MB) into the 256 MB L3 for K2.
__global__ __launch_bounds__(256) void k_gap(const float* __restrict__ x) {
  int wv = threadIdx.x >> 6, lane = threadIdx.x & 63;
  int r0 = blockIdx.x * 16;
#pragma unroll
  for (int it = 0; it < 4; ++it) {
    int row = r0 + wv * 4 + it;
    const float4* xp = (const float4*)x + (size_t)row * 256;
    float s = 0.f;
#pragma unroll
    for (int k = 0; k < 4; ++k) {
      float4 v = xp[lane + 64 * k];
      s += v.x + v.y + v.z + v.w;
    }
    s = wave_reduce(s);
    if (lane == 0) g_gap[row] = s * (1.0f / 1024.0f);
  }
}

// K2: fused q/softmax-moments/output. Block = (n, pblk): 512 ch x 64 pos.
// Thread (cg,pg) caches x[cg*16..+15][pblk*16+pg] in registers (xv[16], 64 VGPR).
// MEASURED toolchain semantics (rounds 3/4): __launch_bounds__ 2nd arg is
// CUDA-style MIN BLOCKS PER CU on this compiler: (512,6)->40 VGPR,
// (512,4)->64 VGPR == 512/(2*arg). So (512,2) -> 2 blocks/CU -> 128 VGPR cap.
// Two-pass phase B (acc[5] = 20 VGPR) keeps true peak ~115 < 128: no spill,
// and the co-resident second block overlaps store tails / serial sections.
__global__ __launch_bounds__(512, 2) void k_fused(const float* __restrict__ x,
                                                  const float* __restrict__ wq,
                                                  const float* __restrict__ bq,
                                                  float* __restrict__ out) {
  int n = blockIdx.x >> 4, pblk = blockIdx.x & 15;
  int t = threadIdx.x;
  int cg = t >> 4, pg = t & 15;
  int wv = t >> 6, lane = t & 63;

  __shared__ float qs[CC];
  __shared__ float wred[8][NJ];
  __shared__ float4 sred[8][16][NJ + 1];  // +1 float4 pad: no 4-way conflict
  __shared__ float4 sfin[16][NJ + 1];
  __shared__ float invZ_sh;

  const float cj[NJ] = {1.f, 1.f, 0.5f, 1.f / 6.f, 1.f / 24.f, 1.f / 120.f,
                        1.f / 720.f, 1.f / 5040.f, 1.f / 40320.f, 1.f / 362880.f};

  // ---- load x tile into registers (read x exactly once in this kernel) ----
  float4 xv[16];
  const float4* x4 = (const float4*)x;
  size_t base = (size_t)(n * CC + cg * 16) * 256 + (size_t)pblk * 16 + pg;
#pragma unroll
  for (int i = 0; i < 16; ++i) xv[i] = x4[base + (size_t)i * 256];

  // ---- phase Q: q = sigmoid(conv5(gap)+b); wave partials of P_j ----
  {
    int c = t;  // 512 threads == 512 channels
    const float* g = g_gap + n * CC;
    float z = bq[0];
#pragma unroll
    for (int k = 0; k < 5; ++k) {
      int idx = c + k - 2;
      float gv = (idx >= 0 && idx < CC) ? g[idx] : 0.f;
      z = fmaf(gv, wq[k], z);
    }
    float qv = 1.f / (1.f + expf(-z));
    qs[c] = qv;
    float pj[NJ];
    float pw = 1.f;
#pragma unroll
    for (int j = 0; j < NJ; ++j) { pj[j] = pw; pw *= qv; }
#pragma unroll
    for (int j = 0; j < NJ; ++j) pj[j] = wave_reduce(pj[j]);
    if (lane == 0) {
#pragma unroll
      for (int j = 0; j < NJ; ++j) wred[wv][j] = pj[j];
    }
  }
  __syncthreads();
  if (t == 0) {
    float Z = 0.f;
#pragma unroll
    for (int j = 0; j < NJ; ++j) {
      float P = 0.f;
#pragma unroll
      for (int w8 = 0; w8 < 8; ++w8) P += wred[w8][j];
      Z = fmaf(cj[j] * P, P, Z);
    }
    invZ_sh = 1.f / Z;  // read after the NEXT __syncthreads
  }

  // ---- phase B: moments in two passes of 5 (acc[5] = 20 VGPR live) ----
#pragma unroll
  for (int half = 0; half < 2; ++half) {
    float4 acc[5];
#pragma unroll
    for (int j = 0; j < 5; ++j) acc[j] = make_float4(0.f, 0.f, 0.f, 0.f);
#pragma unroll
    for (int i = 0; i < 16; ++i) {
      float qc = qs[cg * 16 + i];
      float w;
      if (half == 0) {
        w = 1.f;
      } else {
        float q2 = qc * qc;
        float q4 = q2 * q2;
        w = q4 * qc;  // qc^5
      }
      float4 v = xv[i];
#pragma unroll
      for (int j = 0; j < 5; ++j) {
        acc[j].x = fmaf(w, v.x, acc[j].x);
        acc[j].y = fmaf(w, v.y, acc[j].y);
        acc[j].z = fmaf(w, v.z, acc[j].z);
        acc[j].w = fmaf(w, v.w, acc[j].w);
        w *= qc;
      }
    }
    // reduce over the 4 cg within this wave (lane bits 4,5)
#pragma unroll
    for (int j = 0; j < 5; ++j) {
      acc[j].x += __shfl_xor(acc[j].x, 16, 64);
      acc[j].y += __shfl_xor(acc[j].y, 16, 64);
      acc[j].z += __shfl_xor(acc[j].z, 16, 64);
      acc[j].w += __shfl_xor(acc[j].w, 16, 64);
      acc[j].x += __shfl_xor(acc[j].x, 32, 64);
      acc[j].y += __shfl_xor(acc[j].y, 32, 64);
      acc[j].z += __shfl_xor(acc[j].z, 32, 64);
      acc[j].w += __shfl_xor(acc[j].w, 32, 64);
    }
    if (lane < 16) {
#pragma unroll
      for (int j = 0; j < 5; ++j) sred[wv][lane][half * 5 + j] = acc[j];
    }
  }
  __syncthreads();
  // cross-wave tree: 160 bins (16 pg x 10 j), fold in invZ * 1/j!
  if (t < 160) {
    int pp = t / NJ, j = t - pp * NJ;
    float4 a = make_float4(0.f, 0.f, 0.f, 0.f);
#pragma unroll
    for (int w8 = 0; w8 < 8; ++w8) {
      float4 v = sred[w8][pp][j];
      a.x += v.x; a.y += v.y; a.z += v.z; a.w += v.w;
    }
    float sc = cj[j] * invZ_sh;
    a.x *= sc; a.y *= sc; a.z *= sc; a.w *= sc;
    sfin[pp][j] = a;
  }
  __syncthreads();

  // ---- phase C: out = x * att, x still in registers ----
  float4 sj[NJ];
#pragma unroll
  for (int j = 0; j < NJ; ++j) sj[j] = sfin[pg][j];
  float4* o4 = (float4*)out;
#pragma unroll
  for (int i = 0; i < 16; ++i) {
    float qd = qs[cg * 16 + i];
    float w = 1.f;
    float4 att = make_float4(0.f, 0.f, 0.f, 0.f);
#pragma unroll
    for (int j = 0; j < NJ; ++j) {
      att.x = fmaf(w, sj[j].x, att.x);
      att.y = fmaf(w, sj[j].y, att.y);
      att.z = fmaf(w, sj[j].z, att.z);
      att.w = fmaf(w, sj[j].w, att.w);
      w *= qd;
    }
    float4 xvv = xv[i];
    float4 o;
    o.x = xvv.x * att.x; o.y = xvv.y * att.y;
    o.z = xvv.z * att.z; o.w = xvv.w * att.w;
    o4[base + (size_t)i * 256] = o;
  }
}

extern "C" void kernel_launch(void* const* d_in, const int* in_sizes, int n_in,
                              void* d_out, int out_size, void* d_ws, size_t ws_size,
                              hipStream_t stream) {
  const float* x  = (const float*)d_in[0];
  const float* wq = (const float*)d_in[1];
  const float* bq = (const float*)d_in[2];
  float* out = (float*)d_out;
  (void)d_ws; (void)ws_size;  // workspace intentionally unused

  k_gap<<<NB * CC / 16, 256, 0, stream>>>(x);
  k_fused<<<NB * 16, 512, 0, stream>>>(x, wq, bq, out);
}